// Round 1
// baseline (40919.919 us; speedup 1.0000x reference)
//
#include <hip/hip_runtime.h>
#include <math.h>

// Problem constants
#define B   256
#define T   100
#define IN  132
#define OUT 132
#define H   1024

// GEMM tiles for the gates kernel
#define BM 32    // batch rows per block
#define BJ 32    // hidden-j columns per block (per gate)
#define BN 128   // 4 gates * BJ
#define KT 32    // k-tile

__device__ __forceinline__ float sigmoidf_(float x) {
    return 1.0f / (1.0f + __expf(-x));
}
__device__ __forceinline__ float tanhf_(float x) {
    float e = __expf(2.0f * x);
    return 1.0f - 2.0f / (e + 1.0f);
}

// Zero-init workspace states (h buffers, c, prev_out)
__global__ void init_kernel(float* __restrict__ ws, int n) {
    int i = blockIdx.x * blockDim.x + threadIdx.x;
    int stride = gridDim.x * blockDim.x;
    for (; i < n; i += stride) ws[i] = 0.0f;
}

// One timestep: compute gates for all 3 LSTM cells, update h (into h_nxt) and c (in place).
// grid: (B/BM, H/BJ, 3)   block: 256
__global__ __launch_bounds__(256) void gates_kernel(
    const float* __restrict__ seq,       // [B][T][IN]
    const float* __restrict__ prev_out,  // [B][OUT]
    const float* __restrict__ h_cur,     // [3][B][H]
    float* __restrict__ h_nxt,           // [3][B][H]
    float* __restrict__ c_st,            // [3][B][H]
    const float* __restrict__ Wih0, const float* __restrict__ Whh0,
    const float* __restrict__ bih0, const float* __restrict__ bhh0,
    const float* __restrict__ Wih1, const float* __restrict__ Whh1,
    const float* __restrict__ bih1, const float* __restrict__ bhh1,
    const float* __restrict__ Wih2, const float* __restrict__ Whh2,
    const float* __restrict__ bih2, const float* __restrict__ bhh2,
    const int* __restrict__ cond_num, const int* __restrict__ gt_num,
    int t)
{
    const int l  = blockIdx.z;
    const int j0 = blockIdx.y * BJ;
    const int b0 = blockIdx.x * BM;
    const int tid = threadIdx.x;
    const int tx = tid & 31;   // 32 col-groups (4 cols each)
    const int ty = tid >> 5;   // 8 row-groups  (4 rows each)

    __shared__ float At[KT][BM + 4];   // A^T tile: [k][b], pad to 36 (16B-aligned rows)
    __shared__ float Bt[KT][BN + 4];   // W tile:  [k][c], c = gate*32 + jj, pad to 132

    float acc[4][4];
#pragma unroll
    for (int i = 0; i < 4; ++i)
#pragma unroll
        for (int j = 0; j < 4; ++j) acc[i][j] = 0.0f;

    // Per-cell input selection
    const float* X; int ldx; int Kx;
    const float *Wih, *Whh, *bih, *bhh;
    if (l == 0) {
        const int period = cond_num[0] + gt_num[0];
        const bool use_gt = (t % period) < gt_num[0];
        X   = use_gt ? (seq + (size_t)t * IN) : prev_out;
        ldx = use_gt ? (T * IN) : OUT;
        Kx  = IN;
        Wih = Wih0; Whh = Whh0; bih = bih0; bhh = bhh0;
    } else if (l == 1) {
        X = h_cur + 0 * (size_t)B * H; ldx = H; Kx = H;
        Wih = Wih1; Whh = Whh1; bih = bih1; bhh = bhh1;
    } else {
        X = h_cur + 1 * (size_t)B * H; ldx = H; Kx = H;
        Wih = Wih2; Whh = Whh2; bih = bih2; bhh = bhh2;
    }
    const float* Hs = h_cur + (size_t)l * B * H;

    // Two accumulation phases: x @ Wih^T, then h @ Whh^T
    for (int phase = 0; phase < 2; ++phase) {
        const float* A  = phase ? Hs  : X;
        const int   lda = phase ? H   : ldx;
        const int   Kd  = phase ? H   : Kx;
        const float* W  = phase ? Whh : Wih;
        const int   ldw = Kd;   // W rows have length Kd

        const int nkt = (Kd + KT - 1) / KT;
        for (int kt = 0; kt < nkt; ++kt) {
            const int k0 = kt * KT;
            __syncthreads();
            // Stage A^T (BM x KT -> [k][b]); coalesced on k
#pragma unroll
            for (int r = 0; r < 4; ++r) {
                int i   = r * 256 + tid;
                int row = i >> 5;       // b_local
                int col = i & 31;       // k_local
                int k   = k0 + col;
                float v = (k < Kd) ? A[(size_t)(b0 + row) * lda + k] : 0.0f;
                At[col][row] = v;
            }
            // Stage W tile (BN x KT -> [k][c]); coalesced on k
#pragma unroll
            for (int r = 0; r < 16; ++r) {
                int i  = r * 256 + tid;
                int cc = i >> 5;        // 0..127
                int kk = i & 31;
                int g  = cc >> 5;       // gate
                int jj = cc & 31;
                int k  = k0 + kk;
                int row = g * H + j0 + jj;
                float v = (k < Kd) ? W[(size_t)row * ldw + k] : 0.0f;
                Bt[kk][cc] = v;
            }
            __syncthreads();
#pragma unroll 8
            for (int k = 0; k < KT; ++k) {
                float4 a4 = *(const float4*)&At[k][ty * 4];
                float4 b4 = *(const float4*)&Bt[k][tx * 4];
                float a[4] = {a4.x, a4.y, a4.z, a4.w};
                float b[4] = {b4.x, b4.y, b4.z, b4.w};
#pragma unroll
                for (int ri = 0; ri < 4; ++ri)
#pragma unroll
                    for (int ci = 0; ci < 4; ++ci)
                        acc[ri][ci] += a[ri] * b[ci];
            }
        }
    }

    // Stage raw gates into LDS (reuse Bt as [b_local][c])
    __syncthreads();
#pragma unroll
    for (int ri = 0; ri < 4; ++ri) {
        float4 v = make_float4(acc[ri][0], acc[ri][1], acc[ri][2], acc[ri][3]);
        *(float4*)&Bt[ty * 4 + ri][tx * 4] = v;
    }
    __syncthreads();

    // Elementwise LSTM update: each thread handles 4 (b,j) elements
#pragma unroll
    for (int r = 0; r < 4; ++r) {
        int i  = r * 256 + tid;
        int bl = i >> 5;
        int jl = i & 31;
        int j  = j0 + jl;
        float gi = Bt[bl][0 * 32 + jl] + bih[0 * H + j] + bhh[0 * H + j];
        float gf = Bt[bl][1 * 32 + jl] + bih[1 * H + j] + bhh[1 * H + j];
        float gg = Bt[bl][2 * 32 + jl] + bih[2 * H + j] + bhh[2 * H + j];
        float go = Bt[bl][3 * 32 + jl] + bih[3 * H + j] + bhh[3 * H + j];
        float ii = sigmoidf_(gi);
        float ff = sigmoidf_(gf);
        float g2 = tanhf_(gg);
        float oo = sigmoidf_(go);
        size_t idx = (size_t)l * B * H + (size_t)(b0 + bl) * H + j;
        float cn = ff * c_st[idx] + ii * g2;
        c_st[idx] = cn;
        h_nxt[idx] = oo * tanhf_(cn);
    }
}

// Decoder: out_t = h2 @ W_dec^T + b_dec  -> d_out slice + prev_out
// grid: (B/32, ceil(OUT/32))  block: 256
__global__ __launch_bounds__(256) void decoder_kernel(
    const float* __restrict__ h2,   // [B][H] (new h2)
    const float* __restrict__ Wd,   // [OUT][H]
    const float* __restrict__ bd,   // [OUT]
    float* __restrict__ out,        // [B][T*OUT]
    float* __restrict__ prev_out,   // [B][OUT]
    int t)
{
    const int n0 = blockIdx.x * 32;  // batch tile
    const int m0 = blockIdx.y * 32;  // out-feature tile
    const int tid = threadIdx.x;
    const int tx = tid & 31;         // batch lane
    const int ty = tid >> 5;         // 8 groups x 4 rows = 32 m

    __shared__ float Wt[KT][36];  // [k][m]
    __shared__ float Ht[KT][36];  // [k][n]

    float acc[4] = {0.0f, 0.0f, 0.0f, 0.0f};

    for (int kt = 0; kt < H / KT; ++kt) {
        const int k0 = kt * KT;
        __syncthreads();
#pragma unroll
        for (int r = 0; r < 4; ++r) {
            int i   = r * 256 + tid;
            int row = i >> 5;
            int col = i & 31;
            int m   = m0 + row;
            Wt[col][row] = (m < OUT) ? Wd[(size_t)m * H + k0 + col] : 0.0f;
            Ht[col][row] = h2[(size_t)(n0 + row) * H + k0 + col];
        }
        __syncthreads();
#pragma unroll 8
        for (int k = 0; k < KT; ++k) {
            float4 w4 = *(const float4*)&Wt[k][ty * 4];
            float hn  = Ht[k][tx];
            acc[0] += w4.x * hn;
            acc[1] += w4.y * hn;
            acc[2] += w4.z * hn;
            acc[3] += w4.w * hn;
        }
    }

    const int b = n0 + tx;
#pragma unroll
    for (int ri = 0; ri < 4; ++ri) {
        int m = m0 + ty * 4 + ri;
        if (m < OUT) {
            float v = acc[ri] + bd[m];
            out[(size_t)b * (T * OUT) + (size_t)t * OUT + m] = v;
            prev_out[(size_t)b * OUT + m] = v;
        }
    }
}

extern "C" void kernel_launch(void* const* d_in, const int* in_sizes, int n_in,
                              void* d_out, int out_size, void* d_ws, size_t ws_size,
                              hipStream_t stream) {
    const float* seq  = (const float*)d_in[0];
    const float* Wih0 = (const float*)d_in[1];
    const float* Whh0 = (const float*)d_in[2];
    const float* bih0 = (const float*)d_in[3];
    const float* bhh0 = (const float*)d_in[4];
    const float* Wih1 = (const float*)d_in[5];
    const float* Whh1 = (const float*)d_in[6];
    const float* bih1 = (const float*)d_in[7];
    const float* bhh1 = (const float*)d_in[8];
    const float* Wih2 = (const float*)d_in[9];
    const float* Whh2 = (const float*)d_in[10];
    const float* bih2 = (const float*)d_in[11];
    const float* bhh2 = (const float*)d_in[12];
    const float* Wd   = (const float*)d_in[13];
    const float* bd   = (const float*)d_in[14];
    const int*   cnum = (const int*)d_in[15];
    const int*   gnum = (const int*)d_in[16];

    float* ws   = (float*)d_ws;
    float* h_a  = ws;                          // [3][B][H]
    float* h_b  = h_a + (size_t)3 * B * H;     // [3][B][H]
    float* c_st = h_b + (size_t)3 * B * H;     // [3][B][H]
    float* pout = c_st + (size_t)3 * B * H;    // [B][OUT]
    const int n_init = 3 * 3 * B * H + B * OUT;

    init_kernel<<<512, 256, 0, stream>>>(ws, n_init);

    float* hc = h_a;
    float* hn = h_b;
    float* outp = (float*)d_out;

    for (int t = 0; t < T; ++t) {
        gates_kernel<<<dim3(B / BM, H / BJ, 3), 256, 0, stream>>>(
            seq, pout, hc, hn, c_st,
            Wih0, Whh0, bih0, bhh0,
            Wih1, Whh1, bih1, bhh1,
            Wih2, Whh2, bih2, bhh2,
            cnum, gnum, t);
        decoder_kernel<<<dim3(B / 32, (OUT + 31) / 32), 256, 0, stream>>>(
            hn + (size_t)2 * B * H, Wd, bd, outp, pout, t);
        float* tmp = hc; hc = hn; hn = tmp;
    }
}

// Round 2
// 11118.320 us; speedup vs baseline: 3.6804x; 3.6804x over previous
//
#include <hip/hip_runtime.h>
#include <math.h>

// Problem constants
#define B   256
#define T   100
#define IN  132
#define OUT 132
#define H   1024

typedef __bf16 bf16x8 __attribute__((ext_vector_type(8)));
typedef float  f32x4  __attribute__((ext_vector_type(4)));

#define MFMA(a, b, c) __builtin_amdgcn_mfma_f32_16x16x32_bf16((a), (b), (c), 0, 0, 0)

// LDS row stride (elements) for 32-k chunks: 40*2B=80B, multiple of 16B, odd word-pattern
#define KP 40

__device__ __forceinline__ float sigmoidf_(float x) {
    return 1.0f / (1.0f + __expf(-x));
}
__device__ __forceinline__ float tanhf_(float x) {
    float e = __expf(2.0f * x);
    return 1.0f - 2.0f / (e + 1.0f);
}

// ---------------- prep kernels (once per launch) ----------------

// Split fp32 -> bf16 hi/lo with row/col zero-padding.
// grid: (ceil(dst_k/256), dst_rows), block 256
__global__ void split_pad_kernel(const float* __restrict__ src,
                                 __bf16* __restrict__ hi, __bf16* __restrict__ lo,
                                 int src_rows, int src_k, int dst_k) {
    int k = blockIdx.x * 256 + threadIdx.x;
    int r = blockIdx.y;
    if (k >= dst_k) return;
    float v = (r < src_rows && k < src_k) ? src[(size_t)r * src_k + k] : 0.0f;
    __bf16 h = (__bf16)v;
    hi[(size_t)r * dst_k + k] = h;
    lo[(size_t)r * dst_k + k] = (__bf16)(v - (float)h);
}

__global__ void bias_add_kernel(const float* __restrict__ a, const float* __restrict__ b,
                                float* __restrict__ dst, int n) {
    int i = blockIdx.x * 256 + threadIdx.x;
    if (i < n) dst[i] = a[i] + b[i];
}

__global__ void zero_kernel(float* __restrict__ p, int n) {
    int i = blockIdx.x * blockDim.x + threadIdx.x;
    int st = gridDim.x * blockDim.x;
    for (; i < n; i += st) p[i] = 0.0f;
}

// ---------------- per-step gates kernel ----------------
// grid: (32 j-tiles, 2 m-tiles, 3 cells), block 256 (4 waves)
// Output tile: 128 batch x (4 gates x 32 j). Split-bf16 x3 MFMA products.
__global__ __launch_bounds__(256) void gates_mfma(
    const float* __restrict__ seq,       // [B][T][IN]
    const float* __restrict__ prev_out,  // [B][OUT] fp32
    const __bf16* __restrict__ h_hi, const __bf16* __restrict__ h_lo,   // [3][B][H]
    __bf16* __restrict__ hn_hi, __bf16* __restrict__ hn_lo,             // [3][B][H]
    float* __restrict__ c_st,            // [3][B][H]
    const __bf16* __restrict__ W0_hi, const __bf16* __restrict__ W0_lo, // [4096][160]
    const __bf16* __restrict__ Wb_hi, const __bf16* __restrict__ Wb_lo, // [5][4096][1024]
    const float* __restrict__ bias_comb, // [3][4096]
    const int* __restrict__ cond_num, const int* __restrict__ gt_num,
    int t)
{
    const int j0 = blockIdx.x * 32;   // hidden-j tile
    const int b0 = blockIdx.y * 128;  // batch tile
    const int l  = blockIdx.z;        // cell
    const int tid  = threadIdx.x;
    const int lane = tid & 63;
    const int wv   = tid >> 6;
    const int lx   = lane & 15;
    const int quad = lane >> 4;

    __shared__ __align__(16) __bf16 sA_hi[128 * KP];
    __shared__ __align__(16) __bf16 sA_lo[128 * KP];
    __shared__ __align__(16) __bf16 sB_hi[128 * KP];
    __shared__ __align__(16) __bf16 sB_lo[128 * KP];

    f32x4 acc[2][8];
#pragma unroll
    for (int i = 0; i < 2; ++i)
#pragma unroll
        for (int j = 0; j < 8; ++j) acc[i][j] = (f32x4){0.f, 0.f, 0.f, 0.f};

    const size_t BH  = (size_t)B * H;
    const size_t WSZ = (size_t)4096 * 1024;

    for (int phase = 0; phase < 2; ++phase) {
        bool f32A = (l == 0 && phase == 0);
        const float* Af = nullptr; int ldaf = 0;
        const __bf16 *Ahi = nullptr, *Alo = nullptr;
        const __bf16 *Whi, *Wlo; int ldk, nchunk;
        if (phase == 0) {
            if (l == 0) {
                int cn = cond_num[0], gn = gt_num[0];
                bool ug = (t % (cn + gn)) < gn;
                Af   = ug ? (seq + (size_t)t * IN) : prev_out;
                ldaf = ug ? (T * IN) : OUT;
                Whi = W0_hi; Wlo = W0_lo; ldk = 160; nchunk = 5;
            } else {
                Ahi = h_hi + (size_t)(l - 1) * BH;
                Alo = h_lo + (size_t)(l - 1) * BH;
                int wi = (l == 1) ? 1 : 3;
                Whi = Wb_hi + wi * WSZ; Wlo = Wb_lo + wi * WSZ; ldk = H; nchunk = 32;
            }
        } else {
            Ahi = h_hi + (size_t)l * BH;
            Alo = h_lo + (size_t)l * BH;
            int wi = (l == 0) ? 0 : ((l == 1) ? 2 : 4);
            Whi = Wb_hi + wi * WSZ; Wlo = Wb_lo + wi * WSZ; ldk = H; nchunk = 32;
        }

        for (int kt = 0; kt < nchunk; ++kt) {
            const int k0 = kt * 32;
            __syncthreads();
            // ---- stage B (weights): 128 rows x 32 k, rows = gate*32+jj
#pragma unroll
            for (int s = 0; s < 2; ++s) {
                int idx = s * 256 + tid;
                int row = idx >> 2, seg = idx & 3;
                int g = row >> 5, jj = row & 31;
                size_t off = (size_t)(g * H + j0 + jj) * ldk + k0 + seg * 8;
                *(bf16x8*)&sB_hi[row * KP + seg * 8] = *(const bf16x8*)(Whi + off);
                *(bf16x8*)&sB_lo[row * KP + seg * 8] = *(const bf16x8*)(Wlo + off);
            }
            // ---- stage A (activations)
            if (f32A) {
#pragma unroll
                for (int s = 0; s < 2; ++s) {
                    int idx = s * 256 + tid;
                    int row = idx >> 2, seg = idx & 3;
#pragma unroll
                    for (int e = 0; e < 8; ++e) {
                        int k = k0 + seg * 8 + e;
                        float v = (k < IN) ? Af[(size_t)(b0 + row) * ldaf + k] : 0.0f;
                        __bf16 hv = (__bf16)v;
                        sA_hi[row * KP + seg * 8 + e] = hv;
                        sA_lo[row * KP + seg * 8 + e] = (__bf16)(v - (float)hv);
                    }
                }
            } else {
#pragma unroll
                for (int s = 0; s < 2; ++s) {
                    int idx = s * 256 + tid;
                    int row = idx >> 2, seg = idx & 3;
                    size_t off = (size_t)(b0 + row) * H + k0 + seg * 8;
                    *(bf16x8*)&sA_hi[row * KP + seg * 8] = *(const bf16x8*)(Ahi + off);
                    *(bf16x8*)&sA_lo[row * KP + seg * 8] = *(const bf16x8*)(Alo + off);
                }
            }
            __syncthreads();
            // ---- compute: wave handles 32 batch rows (2 subtiles) x 128 cols (8 subtiles)
            bf16x8 a0h = *(const bf16x8*)&sA_hi[(wv * 32 + lx) * KP + quad * 8];
            bf16x8 a0l = *(const bf16x8*)&sA_lo[(wv * 32 + lx) * KP + quad * 8];
            bf16x8 a1h = *(const bf16x8*)&sA_hi[(wv * 32 + 16 + lx) * KP + quad * 8];
            bf16x8 a1l = *(const bf16x8*)&sA_lo[(wv * 32 + 16 + lx) * KP + quad * 8];
#pragma unroll
            for (int j = 0; j < 8; ++j) {
                bf16x8 bh = *(const bf16x8*)&sB_hi[(j * 16 + lx) * KP + quad * 8];
                bf16x8 bl = *(const bf16x8*)&sB_lo[(j * 16 + lx) * KP + quad * 8];
                acc[0][j] = MFMA(a0h, bh, acc[0][j]);
                acc[1][j] = MFMA(a1h, bh, acc[1][j]);
                acc[0][j] = MFMA(a0h, bl, acc[0][j]);
                acc[1][j] = MFMA(a1h, bl, acc[1][j]);
                acc[0][j] = MFMA(a0l, bh, acc[0][j]);
                acc[1][j] = MFMA(a1l, bh, acc[1][j]);
            }
        }
    }

    // ---- epilogue: lane-local LSTM update (C layout: col=lane&15, row=quad*4+r)
    const float* bc = bias_comb + l * 4 * H;
#pragma unroll
    for (int i = 0; i < 2; ++i) {
#pragma unroll
        for (int hf = 0; hf < 2; ++hf) {
            int jg = j0 + hf * 16 + lx;
            float bi  = bc[0 * H + jg];
            float bff = bc[1 * H + jg];
            float bg  = bc[2 * H + jg];
            float bo  = bc[3 * H + jg];
#pragma unroll
            for (int r = 0; r < 4; ++r) {
                int b = b0 + wv * 32 + i * 16 + quad * 4 + r;
                float gi_ = acc[i][0 + hf][r] + bi;
                float gf_ = acc[i][2 + hf][r] + bff;
                float gg_ = acc[i][4 + hf][r] + bg;
                float go_ = acc[i][6 + hf][r] + bo;
                size_t ix = ((size_t)l * B + b) * H + jg;
                float cn = sigmoidf_(gf_) * c_st[ix] + sigmoidf_(gi_) * tanhf_(gg_);
                c_st[ix] = cn;
                float hval = sigmoidf_(go_) * tanhf_(cn);
                __bf16 hh = (__bf16)hval;
                hn_hi[ix] = hh;
                hn_lo[ix] = (__bf16)(hval - (float)hh);
            }
        }
    }
}

// ---------------- per-step decoder kernel ----------------
// out_t = h2 @ Wdec^T + bd. grid: (2 m-tiles, 5 n-tiles), block 256
__global__ __launch_bounds__(256) void decoder_mfma(
    const __bf16* __restrict__ h2_hi, const __bf16* __restrict__ h2_lo,  // [B][H]
    const __bf16* __restrict__ Wd_hi, const __bf16* __restrict__ Wd_lo,  // [160][1024]
    const float* __restrict__ bd,    // [132]
    float* __restrict__ out,         // [B][T*OUT]
    float* __restrict__ prev_out,    // [B][OUT]
    int t)
{
    const int b0 = blockIdx.x * 128;
    const int n0 = blockIdx.y * 32;
    const int tid  = threadIdx.x;
    const int lane = tid & 63;
    const int wv   = tid >> 6;
    const int lx   = lane & 15;
    const int quad = lane >> 4;

    __shared__ __align__(16) __bf16 sA_hi[128 * KP];
    __shared__ __align__(16) __bf16 sA_lo[128 * KP];
    __shared__ __align__(16) __bf16 sB_hi[32 * KP];
    __shared__ __align__(16) __bf16 sB_lo[32 * KP];

    f32x4 acc[2][2];
#pragma unroll
    for (int i = 0; i < 2; ++i)
#pragma unroll
        for (int j = 0; j < 2; ++j) acc[i][j] = (f32x4){0.f, 0.f, 0.f, 0.f};

    for (int kt = 0; kt < 32; ++kt) {
        const int k0 = kt * 32;
        __syncthreads();
        if (tid < 128) {
            int row = tid >> 2, seg = tid & 3;   // 32 rows x 4 segs
            size_t off = (size_t)(n0 + row) * H + k0 + seg * 8;
            *(bf16x8*)&sB_hi[row * KP + seg * 8] = *(const bf16x8*)(Wd_hi + off);
            *(bf16x8*)&sB_lo[row * KP + seg * 8] = *(const bf16x8*)(Wd_lo + off);
        }
#pragma unroll
        for (int s = 0; s < 2; ++s) {
            int idx = s * 256 + tid;
            int row = idx >> 2, seg = idx & 3;
            size_t off = (size_t)(b0 + row) * H + k0 + seg * 8;
            *(bf16x8*)&sA_hi[row * KP + seg * 8] = *(const bf16x8*)(h2_hi + off);
            *(bf16x8*)&sA_lo[row * KP + seg * 8] = *(const bf16x8*)(h2_lo + off);
        }
        __syncthreads();
        bf16x8 a0h = *(const bf16x8*)&sA_hi[(wv * 32 + lx) * KP + quad * 8];
        bf16x8 a0l = *(const bf16x8*)&sA_lo[(wv * 32 + lx) * KP + quad * 8];
        bf16x8 a1h = *(const bf16x8*)&sA_hi[(wv * 32 + 16 + lx) * KP + quad * 8];
        bf16x8 a1l = *(const bf16x8*)&sA_lo[(wv * 32 + 16 + lx) * KP + quad * 8];
#pragma unroll
        for (int j = 0; j < 2; ++j) {
            bf16x8 bh = *(const bf16x8*)&sB_hi[(j * 16 + lx) * KP + quad * 8];
            bf16x8 bl = *(const bf16x8*)&sB_lo[(j * 16 + lx) * KP + quad * 8];
            acc[0][j] = MFMA(a0h, bh, acc[0][j]);
            acc[1][j] = MFMA(a1h, bh, acc[1][j]);
            acc[0][j] = MFMA(a0h, bl, acc[0][j]);
            acc[1][j] = MFMA(a1h, bl, acc[1][j]);
            acc[0][j] = MFMA(a0l, bh, acc[0][j]);
            acc[1][j] = MFMA(a1l, bh, acc[1][j]);
        }
    }

#pragma unroll
    for (int i = 0; i < 2; ++i) {
#pragma unroll
        for (int j = 0; j < 2; ++j) {
            int n = n0 + j * 16 + lx;
            if (n < OUT) {
#pragma unroll
                for (int r = 0; r < 4; ++r) {
                    int b = b0 + wv * 32 + i * 16 + quad * 4 + r;
                    float val = acc[i][j][r] + bd[n];
                    out[(size_t)b * (T * OUT) + (size_t)t * OUT + n] = val;
                    prev_out[(size_t)b * OUT + n] = val;
                }
            }
        }
    }
}

// ---------------- host launch ----------------

extern "C" void kernel_launch(void* const* d_in, const int* in_sizes, int n_in,
                              void* d_out, int out_size, void* d_ws, size_t ws_size,
                              hipStream_t stream) {
    const float* seq  = (const float*)d_in[0];
    const float* Wih1 = (const float*)d_in[1];
    const float* Whh1 = (const float*)d_in[2];
    const float* bih1 = (const float*)d_in[3];
    const float* bhh1 = (const float*)d_in[4];
    const float* Wih2 = (const float*)d_in[5];
    const float* Whh2 = (const float*)d_in[6];
    const float* bih2 = (const float*)d_in[7];
    const float* bhh2 = (const float*)d_in[8];
    const float* Wih3 = (const float*)d_in[9];
    const float* Whh3 = (const float*)d_in[10];
    const float* bih3 = (const float*)d_in[11];
    const float* bhh3 = (const float*)d_in[12];
    const float* Wd   = (const float*)d_in[13];
    const float* bd   = (const float*)d_in[14];
    const int*   cnum = (const int*)d_in[15];
    const int*   gnum = (const int*)d_in[16];

    // ---- workspace layout (bytes, all 16B-aligned sizes)
    char* p = (char*)d_ws;
    __bf16* W0_hi = (__bf16*)p;  p += (size_t)4096 * 160 * 2;
    __bf16* W0_lo = (__bf16*)p;  p += (size_t)4096 * 160 * 2;
    __bf16* Wb_hi = (__bf16*)p;  p += (size_t)5 * 4096 * 1024 * 2;
    __bf16* Wb_lo = (__bf16*)p;  p += (size_t)5 * 4096 * 1024 * 2;
    __bf16* Wd_hi = (__bf16*)p;  p += (size_t)160 * 1024 * 2;
    __bf16* Wd_lo = (__bf16*)p;  p += (size_t)160 * 1024 * 2;
    float*  bias_comb = (float*)p; p += (size_t)3 * 4096 * 4;
    // mutable state (zeroed below)
    float* state_base = (float*)p;
    __bf16* h_a_hi = (__bf16*)p; p += (size_t)3 * B * H * 2;
    __bf16* h_a_lo = (__bf16*)p; p += (size_t)3 * B * H * 2;
    __bf16* h_b_hi = (__bf16*)p; p += (size_t)3 * B * H * 2;
    __bf16* h_b_lo = (__bf16*)p; p += (size_t)3 * B * H * 2;
    float*  c_st   = (float*)p;  p += (size_t)3 * B * H * 4;
    float*  pout   = (float*)p;  p += (size_t)B * OUT * 4;
    const int state_floats = (int)(((size_t)4 * 3 * B * H * 2 +
                                    (size_t)3 * B * H * 4 +
                                    (size_t)B * OUT * 4) / 4);

    const size_t WSZ = (size_t)4096 * 1024;

    // ---- prep: split weights to bf16 hi/lo (every launch; ws is re-poisoned)
    split_pad_kernel<<<dim3(1, 4096), 256, 0, stream>>>(Wih1, W0_hi, W0_lo, 4096, IN, 160);
    split_pad_kernel<<<dim3(4, 4096), 256, 0, stream>>>(Whh1, Wb_hi + 0 * WSZ, Wb_lo + 0 * WSZ, 4096, H, H);
    split_pad_kernel<<<dim3(4, 4096), 256, 0, stream>>>(Wih2, Wb_hi + 1 * WSZ, Wb_lo + 1 * WSZ, 4096, H, H);
    split_pad_kernel<<<dim3(4, 4096), 256, 0, stream>>>(Whh2, Wb_hi + 2 * WSZ, Wb_lo + 2 * WSZ, 4096, H, H);
    split_pad_kernel<<<dim3(4, 4096), 256, 0, stream>>>(Wih3, Wb_hi + 3 * WSZ, Wb_lo + 3 * WSZ, 4096, H, H);
    split_pad_kernel<<<dim3(4, 4096), 256, 0, stream>>>(Whh3, Wb_hi + 4 * WSZ, Wb_lo + 4 * WSZ, 4096, H, H);
    split_pad_kernel<<<dim3(4, 160), 256, 0, stream>>>(Wd, Wd_hi, Wd_lo, OUT, H, H);
    bias_add_kernel<<<16, 256, 0, stream>>>(bih1, bhh1, bias_comb + 0 * 4096, 4096);
    bias_add_kernel<<<16, 256, 0, stream>>>(bih2, bhh2, bias_comb + 1 * 4096, 4096);
    bias_add_kernel<<<16, 256, 0, stream>>>(bih3, bhh3, bias_comb + 2 * 4096, 4096);
    zero_kernel<<<512, 256, 0, stream>>>(state_base, state_floats);

    __bf16 *hc_hi = h_a_hi, *hc_lo = h_a_lo, *hn_hi = h_b_hi, *hn_lo = h_b_lo;
    float* outp = (float*)d_out;

    for (int t = 0; t < T; ++t) {
        gates_mfma<<<dim3(32, 2, 3), 256, 0, stream>>>(
            seq, pout, hc_hi, hc_lo, hn_hi, hn_lo, c_st,
            W0_hi, W0_lo, Wb_hi, Wb_lo, bias_comb, cnum, gnum, t);
        decoder_mfma<<<dim3(2, 5), 256, 0, stream>>>(
            hn_hi + (size_t)2 * B * H, hn_lo + (size_t)2 * B * H,
            Wd_hi, Wd_lo, bd, outp, pout, t);
        __bf16* tmp;
        tmp = hc_hi; hc_hi = hn_hi; hn_hi = tmp;
        tmp = hc_lo; hc_lo = hn_lo; hn_lo = tmp;
    }
}

// Round 5
// 3951.905 us; speedup vs baseline: 10.3545x; 2.8134x over previous
//
#include <hip/hip_runtime.h>
#include <math.h>

// Problem constants
#define B_   256
#define T_   100
#define IN_  132
#define OUT_ 132
#define H_   1024
#define BH   ((size_t)B_ * H_)
#define WSZ  ((size_t)4096 * H_)

typedef _Float16 f16;
typedef _Float16 f16x8 __attribute__((ext_vector_type(8)));
typedef _Float16 f16x4 __attribute__((ext_vector_type(4)));
typedef float    f32x4 __attribute__((ext_vector_type(4)));

#define MFMA16(a, b, c) __builtin_amdgcn_mfma_f32_16x16x32_f16((a), (b), (c), 0, 0, 0)

#define AS1 __attribute__((address_space(1)))
#define AS3 __attribute__((address_space(3)))

// async global->LDS, 16B per lane; lds dest = wave-uniform base + lane*16
__device__ __forceinline__ void gl_lds16(const void* g, void* l) {
    __builtin_amdgcn_global_load_lds((AS1 void*)g, (AS3 void*)l, 16, 0, 0);
}

__device__ __forceinline__ float sigmoidf_(float x) {
    return 1.0f / (1.0f + __expf(-x));
}
__device__ __forceinline__ float tanhf_(float x) {
    float e = __expf(2.0f * x);
    return 1.0f - 2.0f / (e + 1.0f);
}

// ---------------- prep kernels ----------------

// fp32 -> fp16 with zero padding to [dst_rows][dst_k]; grid (ceil(dst_k/256), dst_rows)
__global__ void conv_pad(const float* __restrict__ src, f16* __restrict__ dst,
                         int src_rows, int src_k, int dst_k) {
    int k = blockIdx.x * 256 + threadIdx.x;
    int r = blockIdx.y;
    if (k >= dst_k) return;
    float v = (r < src_rows && k < src_k) ? src[(size_t)r * src_k + k] : 0.0f;
    dst[(size_t)r * dst_k + k] = (f16)v;
}

__global__ void bias_add_kernel(const float* __restrict__ a, const float* __restrict__ b,
                                float* __restrict__ dst, int n) {
    int i = blockIdx.x * 256 + threadIdx.x;
    if (i < n) dst[i] = a[i] + b[i];
}

__global__ void zero_kernel(float* __restrict__ p, int n) {
    int i = blockIdx.x * blockDim.x + threadIdx.x;
    int st = gridDim.x * blockDim.x;
    for (; i < n; i += st) p[i] = 0.0f;
}

// ---------------- per-step gates GEMM ----------------
// grid (32 j-tiles, 2 m-tiles, 6 instances), block 256 (4 waves, 2x2 of 64x64 tiles).
// Instances: z<3 -> phase1 (h_l @ W_hh_l^T) -> gB ; z>=3 -> phase0 (x/h_{l-1} @ W_ih_l^T) -> gA.
// Tile: 128 batch x 128 cols (4 gates x 32 j). fp16 single product. Double-buffered async LDS.
__global__ __launch_bounds__(256) void gates_mfma(
    const float* __restrict__ seq,      // [B][T][IN]
    const float* __restrict__ outacc,   // [4][256][160] decoder partials (prev step)
    const float* __restrict__ bd,       // [132]
    const f16* __restrict__ h,          // [3][256][1024]
    float* __restrict__ gA, float* __restrict__ gB,   // [3][256][4][1024]
    const f16* __restrict__ W0,         // [4096][160]
    const f16* __restrict__ Wb,         // [5][4096][1024] {Whh1,Wih2,Whh2,Wih3,Whh3}
    const int* __restrict__ cnum, const int* __restrict__ gnum,
    int t)
{
    const int j0   = blockIdx.x * 32;
    const int mb   = blockIdx.y;
    const int z    = blockIdx.z;
    const int tid  = threadIdx.x;
    const int lane = tid & 63;
    const int w    = tid >> 6;
    const int lx   = lane & 15;
    const int quad = lane >> 4;
    const int wrow = w >> 1, wcol = w & 1;

    __shared__ __align__(16) char lds[32768];   // 2 x (A 8KB + B 8KB)

    // ---- instance decode
    int l, nchunk, ldk;
    const f16* Ap; const f16* Wp; float* dst;
    bool special = false;
    if (z < 3) {
        l = z; Ap = h + (size_t)l * BH;
        Wp = Wb + (size_t)(2 * l) * WSZ;          // Whh_l
        dst = gB; ldk = H_; nchunk = 32;
    } else {
        l = z - 3; dst = gA;
        if (l == 0) { special = true; Ap = nullptr; Wp = W0; ldk = 160; nchunk = 5; }
        else {
            Ap = h + (size_t)(l - 1) * BH;
            Wp = Wb + (size_t)(2 * l - 1) * WSZ;  // Wih_l
            ldk = H_; nchunk = 32;
        }
    }

    bool use_gt = false;
    if (special) { int cn = cnum[0], gn = gnum[0]; use_gt = (t % (cn + gn)) < gn; }

    // ---- staging helpers (XOR-swizzled 64B rows: 16B slot s of row r holds k-seg s^(r&3))
    auto stageB = [&](int kt, int buf) {
        char* base = lds + 8192 + buf * 16384;
#pragma unroll
        for (int i = 0; i < 2; ++i) {
            int c  = w * 32 + i * 16 + (lane >> 2);              // tile col 0..127
            int sg = (lane & 3) ^ (c & 3);
            const f16* g = Wp + (size_t)((c >> 5) * H_ + j0 + (c & 31)) * ldk + kt * 32 + sg * 8;
            gl_lds16(g, base + (size_t)(w * 32 + i * 16) * 64);
        }
    };
    auto stageA_async = [&](int kt, int buf) {
        char* base = lds + buf * 16384;
#pragma unroll
        for (int i = 0; i < 2; ++i) {
            int r  = w * 32 + i * 16 + (lane >> 2);              // tile row 0..127
            int sg = (lane & 3) ^ (r & 3);
            const f16* g = Ap + (size_t)(mb * 128 + r) * H_ + kt * 32 + sg * 8;
            gl_lds16(g, base + (size_t)(w * 32 + i * 16) * 64);
        }
    };
    auto stageA_special = [&](int kt, int buf) {
        char* base = lds + buf * 16384;
        // x input: teacher-forced seq (fp32) or reconstructed prev_out (sum of decoder partials)
#pragma unroll
        for (int it = 0; it < 2; ++it) {
            int task = it * 256 + tid;
            int rl = task >> 2, sl = task & 3;
            int sg = sl ^ (rl & 3);
            int b  = mb * 128 + rl;
            f16x8 vv;
#pragma unroll
            for (int e = 0; e < 8; ++e) {
                int k = kt * 32 + sg * 8 + e;
                float v = 0.0f;
                if (k < IN_) {
                    if (use_gt) {
                        v = seq[((size_t)b * T_ + t) * IN_ + k];
                    } else if (t > 0) {
                        v = outacc[(size_t)(0 * 256 + b) * 160 + k]
                          + outacc[(size_t)(1 * 256 + b) * 160 + k]
                          + outacc[(size_t)(2 * 256 + b) * 160 + k]
                          + outacc[(size_t)(3 * 256 + b) * 160 + k] + bd[k];
                    }
                }
                vv[e] = (f16)v;
            }
            *(f16x8*)(base + rl * 64 + sl * 16) = vv;
        }
    };

    f32x4 acc[4][4];
#pragma unroll
    for (int m = 0; m < 4; ++m)
#pragma unroll
        for (int n = 0; n < 4; ++n) acc[m][n] = (f32x4){0.f, 0.f, 0.f, 0.f};

    // prologue: stage chunk 0
    if (special) stageA_special(0, 0); else stageA_async(0, 0);
    stageB(0, 0);

    for (int kt = 0; kt < nchunk; ++kt) {
        __syncthreads();   // drains vmcnt (async loads of chunk kt) + lgkm (ds_writes)
        if (kt + 1 < nchunk) {
            if (special) stageA_special(kt + 1, (kt + 1) & 1);
            else         stageA_async(kt + 1, (kt + 1) & 1);
            stageB(kt + 1, (kt + 1) & 1);
        }
        const char* bA = lds + (kt & 1) * 16384;
        const char* bB = lds + 8192 + (kt & 1) * 16384;
        f16x8 af[4], bf[4];
#pragma unroll
        for (int m = 0; m < 4; ++m) {
            int R = wrow * 64 + m * 16 + lx;
            af[m] = *(const f16x8*)(bA + R * 64 + ((quad ^ (R & 3)) * 16));
        }
#pragma unroll
        for (int n = 0; n < 4; ++n) {
            int R = wcol * 64 + n * 16 + lx;
            bf[n] = *(const f16x8*)(bB + R * 64 + ((quad ^ (R & 3)) * 16));
        }
#pragma unroll
        for (int m = 0; m < 4; ++m)
#pragma unroll
            for (int n = 0; n < 4; ++n)
                acc[m][n] = MFMA16(af[m], bf[n], acc[m][n]);
    }

    // ---- store partial gates (C layout: col=lane&15, row=quad*4+r)
#pragma unroll
    for (int m = 0; m < 4; ++m) {
#pragma unroll
        for (int n = 0; n < 4; ++n) {
            int c = wcol * 64 + n * 16 + lx;
            int g = c >> 5, jj = c & 31;
            size_t coloff = (size_t)g * H_ + j0 + jj;
#pragma unroll
            for (int r = 0; r < 4; ++r) {
                int b = mb * 128 + wrow * 64 + m * 16 + quad * 4 + r;
                dst[((size_t)l * 256 + b) * 4096 + coloff] = acc[m][n][r];
            }
        }
    }
}

// ---------------- per-step LSTM update (+ deferred out write) ----------------
// blocks [0,768): LSTM elementwise update for 3*256*1024 elems (4/thread).
// blocks [768,801): write d_out row t-1 = sum of decoder partials + bias.
__global__ __launch_bounds__(256) void update_kernel(
    const float* __restrict__ gA, const float* __restrict__ gB,
    const float* __restrict__ bias_comb,   // [3][4096]
    f16* __restrict__ h, float* __restrict__ c_st,
    const float* __restrict__ outacc,      // [4][256][160]
    const float* __restrict__ bd,          // [132]
    float* __restrict__ dout,              // [256][T*132]
    int t, int do_lstm, int do_out)
{
    const int bid = blockIdx.x, tid = threadIdx.x;
    if (bid < 768) {
        if (!do_lstm) return;
        int flat = bid * 256 + tid;
        int j4 = flat & 255, b = (flat >> 8) & 255, l = flat >> 16;
        size_t gbase = ((size_t)l * 256 + b) * 4096 + j4 * 4;
        const float* bcl = bias_comb + l * 4096 + j4 * 4;
        f32x4 gi = *(const f32x4*)(gA + gbase)          + *(const f32x4*)(gB + gbase)          + *(const f32x4*)(bcl);
        f32x4 gf = *(const f32x4*)(gA + gbase + 1024)   + *(const f32x4*)(gB + gbase + 1024)   + *(const f32x4*)(bcl + 1024);
        f32x4 gg = *(const f32x4*)(gA + gbase + 2048)   + *(const f32x4*)(gB + gbase + 2048)   + *(const f32x4*)(bcl + 2048);
        f32x4 go = *(const f32x4*)(gA + gbase + 3072)   + *(const f32x4*)(gB + gbase + 3072)   + *(const f32x4*)(bcl + 3072);
        size_t cix = ((size_t)l * 256 + b) * 1024 + j4 * 4;
        f32x4 cv = *(f32x4*)(c_st + cix);
        f16x4 hv;
#pragma unroll
        for (int r = 0; r < 4; ++r) {
            float ii = sigmoidf_(gi[r]);
            float ff = sigmoidf_(gf[r]);
            float g2 = tanhf_(gg[r]);
            float oo = sigmoidf_(go[r]);
            float cn = ff * cv[r] + ii * g2;
            cv[r] = cn;
            hv[r] = (f16)(oo * tanhf_(cn));
        }
        *(f32x4*)(c_st + cix) = cv;
        *(f16x4*)(h + cix) = hv;
    } else {
        if (!do_out) return;
        int flat = (bid - 768) * 256 + tid;
        if (flat >= 8448) return;            // 256 * 33
        int n4 = flat % 33, b = flat / 33;
        int n = n4 * 4;
        f32x4 v = *(const f32x4*)(outacc + (size_t)(0 * 256 + b) * 160 + n)
                + *(const f32x4*)(outacc + (size_t)(1 * 256 + b) * 160 + n)
                + *(const f32x4*)(outacc + (size_t)(2 * 256 + b) * 160 + n)
                + *(const f32x4*)(outacc + (size_t)(3 * 256 + b) * 160 + n)
                + *(const f32x4*)(bd + n);
        *(f32x4*)(dout + (size_t)b * (T_ * OUT_) + (size_t)(t - 1) * OUT_ + n) = v;
    }
}

// ---------------- per-step decoder GEMM (K-split x4, partials) ----------------
// grid (2 m-tiles, 5 n-tiles, 4 k-slices), block 256 (4 waves stacked on M).
__global__ __launch_bounds__(256) void decoder_mfma(
    const f16* __restrict__ h2,     // [256][1024]
    const f16* __restrict__ Wd,     // [160][1024] (rows >=132 zero)
    float* __restrict__ outacc)     // [4][256][160]
{
    const int mb = blockIdx.x;
    const int nb = blockIdx.y;
    const int ks = blockIdx.z;
    const int tid  = threadIdx.x;
    const int lane = tid & 63;
    const int w    = tid >> 6;
    const int lx   = lane & 15;
    const int quad = lane >> 4;

    __shared__ __align__(16) char lds[20480];   // 2 x (A 8KB + B 2KB)

    const int kbase = ks * 256;

    auto stageA = [&](int kt, int buf) {
        char* base = lds + buf * 10240;
#pragma unroll
        for (int i = 0; i < 2; ++i) {
            int r  = w * 32 + i * 16 + (lane >> 2);
            int sg = (lane & 3) ^ (r & 3);
            const f16* g = h2 + (size_t)(mb * 128 + r) * H_ + kbase + kt * 32 + sg * 8;
            gl_lds16(g, base + (size_t)(w * 32 + i * 16) * 64);
        }
    };
    auto stageB = [&](int kt, int buf) {
        char* base = lds + 8192 + buf * 10240;
        if (w < 2) {
            int r  = w * 16 + (lane >> 2);
            int sg = (lane & 3) ^ (r & 3);
            const f16* g = Wd + (size_t)(nb * 32 + r) * H_ + kbase + kt * 32 + sg * 8;
            gl_lds16(g, base + (size_t)(w * 16) * 64);
        }
    };

    f32x4 acc[2][2];
#pragma unroll
    for (int m = 0; m < 2; ++m)
#pragma unroll
        for (int n = 0; n < 2; ++n) acc[m][n] = (f32x4){0.f, 0.f, 0.f, 0.f};

    stageA(0, 0); stageB(0, 0);

    for (int kt = 0; kt < 8; ++kt) {
        __syncthreads();
        if (kt + 1 < 8) { stageA(kt + 1, (kt + 1) & 1); stageB(kt + 1, (kt + 1) & 1); }
        const char* bA = lds + (kt & 1) * 10240;
        const char* bB = lds + 8192 + (kt & 1) * 10240;
        f16x8 af[2], bf[2];
#pragma unroll
        for (int m = 0; m < 2; ++m) {
            int R = w * 32 + m * 16 + lx;
            af[m] = *(const f16x8*)(bA + R * 64 + ((quad ^ (R & 3)) * 16));
        }
#pragma unroll
        for (int n = 0; n < 2; ++n) {
            int R = n * 16 + lx;
            bf[n] = *(const f16x8*)(bB + R * 64 + ((quad ^ (R & 3)) * 16));
        }
#pragma unroll
        for (int m = 0; m < 2; ++m)
#pragma unroll
            for (int n = 0; n < 2; ++n)
                acc[m][n] = MFMA16(af[m], bf[n], acc[m][n]);
    }

#pragma unroll
    for (int m = 0; m < 2; ++m) {
#pragma unroll
        for (int n = 0; n < 2; ++n) {
            int c = nb * 32 + n * 16 + lx;
#pragma unroll
            for (int r = 0; r < 4; ++r) {
                int b = mb * 128 + w * 32 + m * 16 + quad * 4 + r;
                outacc[(size_t)(ks * 256 + b) * 160 + c] = acc[m][n][r];
            }
        }
    }
}

// ---------------- host launch ----------------

extern "C" void kernel_launch(void* const* d_in, const int* in_sizes, int n_in,
                              void* d_out, int out_size, void* d_ws, size_t ws_size,
                              hipStream_t stream) {
    const float* seq  = (const float*)d_in[0];
    const float* Wih1 = (const float*)d_in[1];
    const float* Whh1 = (const float*)d_in[2];
    const float* bih1 = (const float*)d_in[3];
    const float* bhh1 = (const float*)d_in[4];
    const float* Wih2 = (const float*)d_in[5];
    const float* Whh2 = (const float*)d_in[6];
    const float* bih2 = (const float*)d_in[7];
    const float* bhh2 = (const float*)d_in[8];
    const float* Wih3 = (const float*)d_in[9];
    const float* Whh3 = (const float*)d_in[10];
    const float* bih3 = (const float*)d_in[11];
    const float* bhh3 = (const float*)d_in[12];
    const float* Wd   = (const float*)d_in[13];
    const float* bd   = (const float*)d_in[14];
    const int*   cnum = (const int*)d_in[15];
    const int*   gnum = (const int*)d_in[16];

    // ---- workspace layout
    char* p = (char*)d_ws;
    f16*  W0   = (f16*)p;  p += (size_t)4096 * 160 * 2;          // 1.25 MB
    f16*  Wb   = (f16*)p;  p += (size_t)5 * 4096 * 1024 * 2;     // 40 MB
    f16*  Wd16 = (f16*)p;  p += (size_t)160 * 1024 * 2;          // 0.31 MB
    float* bias_comb = (float*)p; p += (size_t)3 * 4096 * 4;     // 48 KB
    float* gAb = (float*)p; p += (size_t)3 * 256 * 4096 * 4;     // 12.6 MB
    float* gBb = (float*)p; p += (size_t)3 * 256 * 4096 * 4;     // 12.6 MB
    float* outacc = (float*)p; p += (size_t)4 * 256 * 160 * 4;   // 0.64 MB
    f16*  h    = (f16*)p;  p += (size_t)3 * 256 * 1024 * 2;      // 1.5 MB
    float* c_st = (float*)p; p += (size_t)3 * 256 * 1024 * 4;    // 3 MB
    const int zero_floats = (int)(((size_t)3 * 256 * 1024 * 2 + (size_t)3 * 256 * 1024 * 4) / 4);

    // ---- prep
    conv_pad<<<dim3(1, 4096), 256, 0, stream>>>(Wih1, W0, 4096, IN_, 160);
    conv_pad<<<dim3(4, 4096), 256, 0, stream>>>(Whh1, Wb + 0 * WSZ, 4096, H_, H_);
    conv_pad<<<dim3(4, 4096), 256, 0, stream>>>(Wih2, Wb + 1 * WSZ, 4096, H_, H_);
    conv_pad<<<dim3(4, 4096), 256, 0, stream>>>(Whh2, Wb + 2 * WSZ, 4096, H_, H_);
    conv_pad<<<dim3(4, 4096), 256, 0, stream>>>(Wih3, Wb + 3 * WSZ, 4096, H_, H_);
    conv_pad<<<dim3(4, 4096), 256, 0, stream>>>(Whh3, Wb + 4 * WSZ, 4096, H_, H_);
    conv_pad<<<dim3(4, 160), 256, 0, stream>>>(Wd, Wd16, OUT_, H_, H_);
    bias_add_kernel<<<16, 256, 0, stream>>>(bih1, bhh1, bias_comb + 0 * 4096, 4096);
    bias_add_kernel<<<16, 256, 0, stream>>>(bih2, bhh2, bias_comb + 1 * 4096, 4096);
    bias_add_kernel<<<16, 256, 0, stream>>>(bih3, bhh3, bias_comb + 2 * 4096, 4096);
    zero_kernel<<<512, 256, 0, stream>>>((float*)h, zero_floats);   // h + c contiguous

    float* dout = (float*)d_out;

    for (int t = 0; t < T_; ++t) {
        gates_mfma<<<dim3(32, 2, 6), 256, 0, stream>>>(
            seq, outacc, bd, h, gAb, gBb, W0, Wb, cnum, gnum, t);
        update_kernel<<<801, 256, 0, stream>>>(
            gAb, gBb, bias_comb, h, c_st, outacc, bd, dout, t, 1, (t > 0) ? 1 : 0);
        decoder_mfma<<<dim3(2, 5, 4), 256, 0, stream>>>(
            h + 2 * BH, Wd16, outacc);
    }
    // flush the last output row (t-1 = 99)
    update_kernel<<<801, 256, 0, stream>>>(
        gAb, gBb, bias_comb, h, c_st, outacc, bd, dout, T_, 0, 1);
}

// Round 6
// 3392.377 us; speedup vs baseline: 12.0623x; 1.1649x over previous
//
#include <hip/hip_runtime.h>
#include <math.h>

// Problem constants
#define B_   256
#define T_   100
#define IN_  132
#define OUT_ 132
#define H_   1024
#define BH   ((size_t)B_ * H_)
#define WSZ  ((size_t)4096 * H_)

typedef _Float16 f16;
typedef _Float16 f16x8 __attribute__((ext_vector_type(8)));
typedef float    f32x4 __attribute__((ext_vector_type(4)));

#define MFMA16(a, b, c) __builtin_amdgcn_mfma_f32_16x16x32_f16((a), (b), (c), 0, 0, 0)

#define AS1 __attribute__((address_space(1)))
#define AS3 __attribute__((address_space(3)))

__device__ __forceinline__ void gl_lds16(const void* g, void* l) {
    __builtin_amdgcn_global_load_lds((AS1 void*)g, (AS3 void*)l, 16, 0, 0);
}

__device__ __forceinline__ float sigmoidf_(float x) {
    return 1.0f / (1.0f + __expf(-x));
}
__device__ __forceinline__ float tanhf_(float x) {
    float e = __expf(2.0f * x);
    return 1.0f - 2.0f / (e + 1.0f);
}

// ---------------- prep kernels ----------------

__global__ void conv_pad(const float* __restrict__ src, f16* __restrict__ dst,
                         int src_rows, int src_k, int dst_k) {
    int k = blockIdx.x * 256 + threadIdx.x;
    int r = blockIdx.y;
    if (k >= dst_k) return;
    float v = (r < src_rows && k < src_k) ? src[(size_t)r * src_k + k] : 0.0f;
    dst[(size_t)r * dst_k + k] = (f16)v;
}

// WdT[m][k] = Wd[k][m], padded to k<160. grid (1, 1024), block 256
__global__ void convT_kernel(const float* __restrict__ Wd, f16* __restrict__ WdT) {
    int k = blockIdx.x * 256 + threadIdx.x;
    int m = blockIdx.y;
    if (k >= 160) return;
    float v = (k < IN_) ? Wd[(size_t)k * H_ + m] : 0.0f;
    WdT[(size_t)m * 160 + k] = (f16)v;
}

__global__ void bias_add_kernel(const float* __restrict__ a, const float* __restrict__ b,
                                float* __restrict__ dst, int n) {
    int i = blockIdx.x * 256 + threadIdx.x;
    if (i < n) dst[i] = a[i] + b[i];
}

// bfb[j] = sum_k Wih1[j][k] * bd[k]
__global__ void bfb_kernel(const float* __restrict__ Wih1, const float* __restrict__ bd,
                           float* __restrict__ bfb) {
    int j = blockIdx.x * 256 + threadIdx.x;
    if (j >= 4096) return;
    float s = 0.0f;
    for (int k = 0; k < IN_; ++k) s += Wih1[(size_t)j * IN_ + k] * bd[k];
    bfb[j] = s;
}

__global__ void zero_kernel(float* __restrict__ p, int n) {
    int i = blockIdx.x * blockDim.x + threadIdx.x;
    int st = gridDim.x * blockDim.x;
    for (; i < n; i += st) p[i] = 0.0f;
}

// Wfb = W0(fp16,[4096][160]) @ WdT(fp16,[1024][160])^T -> [4096][1024] fp16
// grid (32 m-tiles, 8 n-tiles), block 256 (4 waves 2x2 of 64x64)
__global__ __launch_bounds__(256) void wfb_mfma(
    const f16* __restrict__ W0, const f16* __restrict__ WdT, f16* __restrict__ Wfb)
{
    const int m0 = blockIdx.x * 128;
    const int n0 = blockIdx.y * 128;
    const int tid  = threadIdx.x;
    const int lane = tid & 63;
    const int w    = tid >> 6;
    const int lx   = lane & 15;
    const int quad = lane >> 4;
    const int wrow = w >> 1, wcol = w & 1;

    __shared__ __align__(16) char lds[32768];   // 2 x (A 8KB + B 8KB)

    auto stA = [&](int kt, int buf) {
        char* base = lds + buf * 16384;
#pragma unroll
        for (int i = 0; i < 2; ++i) {
            int r  = w * 32 + i * 16 + (lane >> 2);
            int sg = (lane & 3) ^ (r & 3);
            const f16* g = W0 + (size_t)(m0 + r) * 160 + kt * 32 + sg * 8;
            gl_lds16(g, base + (size_t)(w * 32 + i * 16) * 64);
        }
    };
    auto stB = [&](int kt, int buf) {
        char* base = lds + 8192 + buf * 16384;
#pragma unroll
        for (int i = 0; i < 2; ++i) {
            int r  = w * 32 + i * 16 + (lane >> 2);
            int sg = (lane & 3) ^ (r & 3);
            const f16* g = WdT + (size_t)(n0 + r) * 160 + kt * 32 + sg * 8;
            gl_lds16(g, base + (size_t)(w * 32 + i * 16) * 64);
        }
    };

    f32x4 acc[4][4];
#pragma unroll
    for (int m = 0; m < 4; ++m)
#pragma unroll
        for (int n = 0; n < 4; ++n) acc[m][n] = (f32x4){0.f, 0.f, 0.f, 0.f};

    stA(0, 0); stB(0, 0);
    for (int kt = 0; kt < 5; ++kt) {
        __syncthreads();
        if (kt + 1 < 5) { stA(kt + 1, (kt + 1) & 1); stB(kt + 1, (kt + 1) & 1); }
        const char* bA = lds + (kt & 1) * 16384;
        const char* bB = lds + 8192 + (kt & 1) * 16384;
        f16x8 af[4], bf[4];
#pragma unroll
        for (int m = 0; m < 4; ++m) {
            int R = wrow * 64 + m * 16 + lx;
            af[m] = *(const f16x8*)(bA + R * 64 + ((quad ^ (R & 3)) * 16));
        }
#pragma unroll
        for (int n = 0; n < 4; ++n) {
            int R = wcol * 64 + n * 16 + lx;
            bf[n] = *(const f16x8*)(bB + R * 64 + ((quad ^ (R & 3)) * 16));
        }
#pragma unroll
        for (int m = 0; m < 4; ++m)
#pragma unroll
            for (int n = 0; n < 4; ++n)
                acc[m][n] = MFMA16(af[m], bf[n], acc[m][n]);
    }

#pragma unroll
    for (int m = 0; m < 4; ++m)
#pragma unroll
        for (int n = 0; n < 4; ++n)
#pragma unroll
            for (int r = 0; r < 4; ++r) {
                int row = m0 + wrow * 64 + m * 16 + quad * 4 + r;
                int col = n0 + wcol * 64 + n * 16 + lx;
                Wfb[(size_t)row * H_ + col] = (f16)acc[m][n][r];
            }
}

// ---------------- fused per-step kernel ----------------
// grid (32 j-tiles, 4 m-tiles(64 rows), 3 cells), block 256 (4 waves 2x2).
// Tile: 64 batch x 128 cols; col c -> gate=(c>>4)&3, jj=(c&15)+(c>>6)*16
// (each wave's lanes see all 4 gates of one (b,j) -> lane-local LSTM update).
// K-loop: phase0 (x/h_{l-1}/h2fb @ Wih/Wfb) then phase1 (h_l @ Whh), flat.
__global__ __launch_bounds__(256) void step_mfma(
    const float* __restrict__ seq,    // [B][T][IN]
    const f16* __restrict__ hfb,      // h2(t-1) for feedback (valid t>0)
    const f16* __restrict__ h2old,    // h2(t-1) for cell2 phase1 (zeros at t=0)
    const f16* __restrict__ h01c,     // [2][BH] old h0,h1
    f16* __restrict__ h01n,           // [2][BH] new h0,h1
    f16* __restrict__ h2out,          // hist + t*BH
    float* __restrict__ c_st,         // [3][B][H]
    const f16* __restrict__ W0,       // [4096][160]  (Wih1 padded)
    const f16* __restrict__ Wb,       // [5][4096][1024] {Whh1,Wih2,Whh2,Wih3,Whh3}
    const f16* __restrict__ Wfb,      // [4096][1024]  (Wih1 @ Wd)
    const float* __restrict__ bias_comb,  // [3][4096]
    const float* __restrict__ bfb,        // [4096]
    const int* __restrict__ cnum, const int* __restrict__ gnum,
    int t)
{
    const int j0   = blockIdx.x * 32;
    const int mb   = blockIdx.y;
    const int l    = blockIdx.z;
    const int tid  = threadIdx.x;
    const int lane = tid & 63;
    const int w    = tid >> 6;
    const int lx   = lane & 15;
    const int quad = lane >> 4;
    const int wrow = w >> 1, wcol = w & 1;

    __shared__ __align__(16) char lds[24576];   // 2 x (A 4KB + B 8KB)

    // ---- phase decode
    bool use_gt = false, seqmode = false;
    int n0 = 32, ldk0 = H_;
    const f16 *Ap0 = nullptr, *Wp0 = nullptr;
    if (l == 0) {
        int cn = cnum[0], gn = gnum[0];
        use_gt = (t % (cn + gn)) < gn;
        if (use_gt)      { seqmode = true; Wp0 = W0; ldk0 = 160; n0 = 5; }
        else if (t == 0) { n0 = 0; }
        else             { Ap0 = hfb; Wp0 = Wfb; }
    } else if (l == 1) { Ap0 = h01c;      Wp0 = Wb + 1 * WSZ; }
    else               { Ap0 = h01c + BH; Wp0 = Wb + 3 * WSZ; }
    const f16* Ap1 = (l == 0) ? h01c : (l == 1) ? (h01c + BH) : h2old;
    const f16* Wp1 = Wb + (size_t)((l == 0) ? 0 : (l == 1) ? 2 : 4) * WSZ;
    const int ntot = n0 + 32;

    // ---- staging (XOR-swizzled 64B rows)
    auto stA = [&](const f16* Ap, int kk, int buf) {
        char* base = lds + buf * 12288 + w * 1024;   // wave rows [w*16, +16)
        int row = w * 16 + (lane >> 2);
        int sg  = (lane & 3) ^ (row & 3);
        const f16* g = Ap + (size_t)(mb * 64 + row) * H_ + kk * 32 + sg * 8;
        gl_lds16(g, base);
    };
    auto stAseq = [&](int kk, int buf) {
        char* base = lds + buf * 12288;
        int rl = tid >> 2, sl = tid & 3;
        int sg = sl ^ (rl & 3);
        int b  = mb * 64 + rl;
        f16x8 vv;
#pragma unroll
        for (int e = 0; e < 8; ++e) {
            int k = kk * 32 + sg * 8 + e;
            float v = (k < IN_) ? seq[((size_t)b * T_ + t) * IN_ + k] : 0.0f;
            vv[e] = (f16)v;
        }
        *(f16x8*)(base + rl * 64 + sl * 16) = vv;
    };
    auto stB = [&](const f16* Wp, size_t ldk, int kk, int buf) {
        char* base = lds + 4096 + buf * 12288;
#pragma unroll
        for (int i = 0; i < 2; ++i) {
            int c    = w * 32 + i * 16 + (lane >> 2);
            int sg   = (lane & 3) ^ (c & 3);
            int gate = (c >> 4) & 3;
            int jj   = (c & 15) + (c >> 6) * 16;
            const f16* g = Wp + (size_t)(gate * H_ + j0 + jj) * ldk + kk * 32 + sg * 8;
            gl_lds16(g, base + (size_t)(w * 32 + i * 16) * 64);
        }
    };
    auto stage = [&](int kt, int buf) {
        if (kt < n0) {
            if (seqmode) stAseq(kt, buf); else stA(Ap0, kt, buf);
            stB(Wp0, (size_t)ldk0, kt, buf);
        } else {
            stA(Ap1, kt - n0, buf);
            stB(Wp1, (size_t)H_, kt - n0, buf);
        }
    };

    f32x4 acc[2][4];
#pragma unroll
    for (int m = 0; m < 2; ++m)
#pragma unroll
        for (int n = 0; n < 4; ++n) acc[m][n] = (f32x4){0.f, 0.f, 0.f, 0.f};

    stage(0, 0);
    for (int kt = 0; kt < ntot; ++kt) {
        __syncthreads();
        if (kt + 1 < ntot) stage(kt + 1, (kt + 1) & 1);
        const char* bA = lds + (kt & 1) * 12288;
        const char* bB = lds + 4096 + (kt & 1) * 12288;
        f16x8 af[2], bf[4];
#pragma unroll
        for (int m = 0; m < 2; ++m) {
            int R = wrow * 32 + m * 16 + lx;
            af[m] = *(const f16x8*)(bA + R * 64 + ((quad ^ (R & 3)) * 16));
        }
#pragma unroll
        for (int n = 0; n < 4; ++n) {
            int R = wcol * 64 + n * 16 + lx;
            bf[n] = *(const f16x8*)(bB + R * 64 + ((quad ^ (R & 3)) * 16));
        }
#pragma unroll
        for (int m = 0; m < 2; ++m)
#pragma unroll
            for (int n = 0; n < 4; ++n)
                acc[m][n] = MFMA16(af[m], bf[n], acc[m][n]);
    }

    // ---- lane-local LSTM epilogue (C layout: col=lane&15, row=quad*4+r; gate=n)
    const int j = j0 + wcol * 16 + lx;
    const float* bc = bias_comb + l * 4096;
    const bool addfb = (l == 0 && !use_gt && t > 0);
    float bi  = bc[j]        + (addfb ? bfb[j]        : 0.f);
    float bff = bc[1024 + j] + (addfb ? bfb[1024 + j] : 0.f);
    float bg  = bc[2048 + j] + (addfb ? bfb[2048 + j] : 0.f);
    float bo  = bc[3072 + j] + (addfb ? bfb[3072 + j] : 0.f);
#pragma unroll
    for (int m = 0; m < 2; ++m) {
#pragma unroll
        for (int r = 0; r < 4; ++r) {
            int b = mb * 64 + wrow * 32 + m * 16 + quad * 4 + r;
            float gi = acc[m][0][r] + bi;
            float gf = acc[m][1][r] + bff;
            float gg = acc[m][2][r] + bg;
            float go = acc[m][3][r] + bo;
            size_t ix = ((size_t)l * B_ + b) * H_ + j;
            float cn = sigmoidf_(gf) * c_st[ix] + sigmoidf_(gi) * tanhf_(gg);
            c_st[ix] = cn;
            float hv = sigmoidf_(go) * tanhf_(cn);
            if (l == 2) h2out[(size_t)b * H_ + j] = (f16)hv;
            else        h01n[(size_t)l * BH + (size_t)b * H_ + j] = (f16)hv;
        }
    }
}

// ---------------- final batched decoder ----------------
// out[b][t][n] = hist[t][b][:] @ Wd^T + bd. M=25600 rows (t*256+b), N=160(132), K=1024.
// grid (200, 5), block 256 (4 waves stacked on M; tile 128x32).
__global__ __launch_bounds__(256) void decode_mfma(
    const f16* __restrict__ hist,   // [100][256][1024]
    const f16* __restrict__ Wd16,   // [160][1024]
    const float* __restrict__ bd,   // [132]
    float* __restrict__ dout)       // [256][T*132]
{
    const int r0  = blockIdx.x * 128;
    const int nb0 = blockIdx.y * 32;
    const int tid  = threadIdx.x;
    const int lane = tid & 63;
    const int w    = tid >> 6;
    const int lx   = lane & 15;
    const int quad = lane >> 4;

    __shared__ __align__(16) char lds[20480];   // 2 x (A 8KB + B 2KB)

    auto stA = [&](int kt, int buf) {
        char* base = lds + buf * 10240;
#pragma unroll
        for (int i = 0; i < 2; ++i) {
            int r  = w * 32 + i * 16 + (lane >> 2);
            int sg = (lane & 3) ^ (r & 3);
            const f16* g = hist + (size_t)(r0 + r) * H_ + kt * 32 + sg * 8;
            gl_lds16(g, base + (size_t)(w * 32 + i * 16) * 64);
        }
    };
    auto stB = [&](int kt, int buf) {
        char* base = lds + 8192 + buf * 10240;
        if (w < 2) {
            int r  = w * 16 + (lane >> 2);
            int sg = (lane & 3) ^ (r & 3);
            const f16* g = Wd16 + (size_t)(nb0 + r) * H_ + kt * 32 + sg * 8;
            gl_lds16(g, base + (size_t)(w * 16) * 64);
        }
    };

    f32x4 acc[2][2];
#pragma unroll
    for (int m = 0; m < 2; ++m)
#pragma unroll
        for (int n = 0; n < 2; ++n) acc[m][n] = (f32x4){0.f, 0.f, 0.f, 0.f};

    stA(0, 0); stB(0, 0);
    for (int kt = 0; kt < 32; ++kt) {
        __syncthreads();
        if (kt + 1 < 32) { stA(kt + 1, (kt + 1) & 1); stB(kt + 1, (kt + 1) & 1); }
        const char* bA = lds + (kt & 1) * 10240;
        const char* bB = lds + 8192 + (kt & 1) * 10240;
        f16x8 af[2], bf[2];
#pragma unroll
        for (int m = 0; m < 2; ++m) {
            int R = w * 32 + m * 16 + lx;
            af[m] = *(const f16x8*)(bA + R * 64 + ((quad ^ (R & 3)) * 16));
        }
#pragma unroll
        for (int n = 0; n < 2; ++n) {
            int R = n * 16 + lx;
            bf[n] = *(const f16x8*)(bB + R * 64 + ((quad ^ (R & 3)) * 16));
        }
#pragma unroll
        for (int m = 0; m < 2; ++m)
#pragma unroll
            for (int n = 0; n < 2; ++n)
                acc[m][n] = MFMA16(af[m], bf[n], acc[m][n]);
    }

#pragma unroll
    for (int n = 0; n < 2; ++n) {
        int nn = nb0 + n * 16 + lx;
        if (nn < OUT_) {
            float bv = bd[nn];
#pragma unroll
            for (int m = 0; m < 2; ++m)
#pragma unroll
                for (int r = 0; r < 4; ++r) {
                    int row = r0 + w * 32 + m * 16 + quad * 4 + r;
                    int tt = row >> 8, b = row & 255;
                    dout[(size_t)b * (T_ * OUT_) + (size_t)tt * OUT_ + nn] = acc[m][n][r] + bv;
                }
        }
    }
}

// ---------------- host launch ----------------

extern "C" void kernel_launch(void* const* d_in, const int* in_sizes, int n_in,
                              void* d_out, int out_size, void* d_ws, size_t ws_size,
                              hipStream_t stream) {
    const float* seq  = (const float*)d_in[0];
    const float* Wih1 = (const float*)d_in[1];
    const float* Whh1 = (const float*)d_in[2];
    const float* bih1 = (const float*)d_in[3];
    const float* bhh1 = (const float*)d_in[4];
    const float* Wih2 = (const float*)d_in[5];
    const float* Whh2 = (const float*)d_in[6];
    const float* bih2 = (const float*)d_in[7];
    const float* bhh2 = (const float*)d_in[8];
    const float* Wih3 = (const float*)d_in[9];
    const float* Whh3 = (const float*)d_in[10];
    const float* bih3 = (const float*)d_in[11];
    const float* bhh3 = (const float*)d_in[12];
    const float* Wd   = (const float*)d_in[13];
    const float* bd   = (const float*)d_in[14];
    const int*   cnum = (const int*)d_in[15];
    const int*   gnum = (const int*)d_in[16];

    // ---- workspace layout
    char* p = (char*)d_ws;
    f16*  W0   = (f16*)p;  p += (size_t)4096 * 160 * 2;          // 1.31 MB
    f16*  Wb   = (f16*)p;  p += (size_t)5 * 4096 * 1024 * 2;     // 41.9 MB
    f16*  Wd16 = (f16*)p;  p += (size_t)160 * 1024 * 2;          // 0.33 MB
    f16*  WdT  = (f16*)p;  p += (size_t)1024 * 160 * 2;          // 0.33 MB
    f16*  Wfb  = (f16*)p;  p += (size_t)4096 * 1024 * 2;         // 8.39 MB
    float* bias_comb = (float*)p; p += (size_t)3 * 4096 * 4;     // 48 KB
    float* bfb = (float*)p; p += (size_t)4096 * 4;               // 16 KB
    f16*  hist = (f16*)p;  p += (size_t)100 * BH * 2;            // 52.4 MB
    f16*  h01a = (f16*)p;  p += (size_t)2 * BH * 2;              // 1.05 MB (zeroed)
    f16*  h01b = (f16*)p;  p += (size_t)2 * BH * 2;              // 1.05 MB
    float* c_st = (float*)p; p += (size_t)3 * BH * 4;            // 3.15 MB
    // zero region: h01a + h01b + c (contiguous)
    const int zero_floats = (int)(((size_t)4 * BH * 2 + (size_t)3 * BH * 4) / 4);

    // ---- prep
    conv_pad<<<dim3(1, 4096), 256, 0, stream>>>(Wih1, W0, 4096, IN_, 160);
    conv_pad<<<dim3(4, 4096), 256, 0, stream>>>(Whh1, Wb + 0 * WSZ, 4096, H_, H_);
    conv_pad<<<dim3(4, 4096), 256, 0, stream>>>(Wih2, Wb + 1 * WSZ, 4096, H_, H_);
    conv_pad<<<dim3(4, 4096), 256, 0, stream>>>(Whh2, Wb + 2 * WSZ, 4096, H_, H_);
    conv_pad<<<dim3(4, 4096), 256, 0, stream>>>(Wih3, Wb + 3 * WSZ, 4096, H_, H_);
    conv_pad<<<dim3(4, 4096), 256, 0, stream>>>(Whh3, Wb + 4 * WSZ, 4096, H_, H_);
    conv_pad<<<dim3(4, 160), 256, 0, stream>>>(Wd, Wd16, OUT_, H_, H_);
    convT_kernel<<<dim3(1, 1024), 256, 0, stream>>>(Wd, WdT);
    bias_add_kernel<<<16, 256, 0, stream>>>(bih1, bhh1, bias_comb + 0 * 4096, 4096);
    bias_add_kernel<<<16, 256, 0, stream>>>(bih2, bhh2, bias_comb + 1 * 4096, 4096);
    bias_add_kernel<<<16, 256, 0, stream>>>(bih3, bhh3, bias_comb + 2 * 4096, 4096);
    bfb_kernel<<<16, 256, 0, stream>>>(Wih1, bd, bfb);
    wfb_mfma<<<dim3(32, 8), 256, 0, stream>>>(W0, WdT, Wfb);
    zero_kernel<<<512, 256, 0, stream>>>((float*)h01a, zero_floats);

    f16 *hc = h01a, *hn = h01b;
    for (int t = 0; t < T_; ++t) {
        const f16* hfb   = (t > 0) ? (hist + (size_t)(t - 1) * BH) : hc;  // unused at t=0
        const f16* h2old = (t > 0) ? (hist + (size_t)(t - 1) * BH) : hc;  // zeros at t=0
        step_mfma<<<dim3(32, 4, 3), 256, 0, stream>>>(
            seq, hfb, h2old, hc, hn, hist + (size_t)t * BH, c_st,
            W0, Wb, Wfb, bias_comb, bfb, cnum, gnum, t);
        f16* tmp = hc; hc = hn; hn = tmp;
    }

    decode_mfma<<<dim3(200, 5), 256, 0, stream>>>(hist, Wd16, bd, (float*)d_out);
}